// Round 7
// baseline (306.364 us; speedup 1.0000x reference)
//
#include <hip/hip_runtime.h>
#include <hip/hip_bf16.h>

#define LSEQ 2048
#define BB   2048
#define TT   7
#define REC  52   // 49 matrix + scale + score + maskcnt (float), 208 B = 16B-aligned

// ---------------------------------------------------------------------------
// Kernel 1: 2 threads per (batch, chunk); thread h in {0,1} builds the
// composite operator for its half-chunk (C/2 steps) in exp-space:
//   M <- (M x E) o colscale(exp(em_i)),  E = exp(transitions) per cont flag.
// E is held in SGPRs via readfirstlane when the cont flag is wave-uniform
// (the common case); a register-light LDS fallback handles divergence.
// Each half renormalizes, then h=1 publishes via LDS and h=0 merges
// (M = MA x MB), renorms again, and writes the 52-float record.
// ---------------------------------------------------------------------------
template<int K>
__global__ __launch_bounds__(256, 4)
void crf_chunk_kernel(const float* __restrict__ em,
                      const int*   __restrict__ tags,
                      const int*   __restrict__ qmask,
                      const int*   __restrict__ mask,
                      const float* __restrict__ self_t,
                      const float* __restrict__ other_t,
                      float* __restrict__ recs) {
  constexpr int C  = LSEQ / K;   // steps per chunk
  constexpr int C2 = C / 2;      // steps per thread
  __shared__ float sE[2][49];    // exp(transitions): [0]=self, [1]=other
  __shared__ float sT[2][49];    // raw transitions (gold-path score)
  __shared__ float sMB[128][49]; // second-half matrices (stride 49: 2-way banks, free)
  __shared__ float sAux[128][3]; // sc, mc, logscale from h=1

  int tid = threadIdx.x;
  if (tid < 49) {
    float sv = self_t[tid];
    float ov = other_t[tid];
    sE[0][tid] = __expf(sv);
    sE[1][tid] = __expf(ov);
    sT[0][tid] = sv;
    sT[1][tid] = ov;
  }
  __syncthreads();

  int h  = tid >> 7;             // half: 0 = first C/2 steps, 1 = second
  int bl = tid & 127;            // chunk slot within block
  int chunkIdx = blockIdx.x * 128 + bl;
  int b = chunkIdx & (BB - 1);   // varies across lanes
  int c = chunkIdx >> 11;        // uniform within block (2048 % 128 == 0)

  float M[49];
#pragma unroll
  for (int s = 0; s < 7; ++s)
#pragma unroll
    for (int t = 0; t < 7; ++t) M[s*7+t] = (s == t) ? 1.0f : 0.0f;

  float sc = 0.0f;
  int   mc = 0;
  int i0    = c * C + h * C2;
  int i_end = i0 + C2;
  int tp, qp;
  if (i0 == 0) {                 // c==0, h==0: step 0 is the alpha-init
    mc = mask[b];
    tp = tags[b];
    qp = qmask[b];
    i0 = 1;
  } else {
    tp = tags[(size_t)(i0 - 1) * BB + b];
    qp = qmask[(size_t)(i0 - 1) * BB + b];
  }

  const float* em_p = em    + ((size_t)i0 * BB + b) * TT;
  const int*   qm_p = qmask + (size_t)i0 * BB + b;
  const int*   mk_p = mask  + (size_t)i0 * BB + b;
  const int*   tg_p = tags  + (size_t)i0 * BB + b;

  float Es[49];                  // SGPR-resident when cont is wave-uniform
  int loadedCont = -1;

  // software pipeline: current step's inputs in regs, next prefetched
  float ec[7];
#pragma unroll
  for (int t = 0; t < 7; ++t) ec[t] = em_p[t];
  int tg = *tg_p, qm = *qm_p, mi = *mk_p;

  for (int i = i0; i < i_end; ++i) {
    em_p += (size_t)BB * TT;
    qm_p += BB; mk_p += BB; tg_p += BB;
    float en[7]; int ntg = 0, nqm = 0, nmi = 0;
    bool more = (i + 1 < i_end);          // uniform (c,h uniform per wave)
    if (more) {
#pragma unroll
      for (int t = 0; t < 7; ++t) en[t] = em_p[t];
      ntg = *tg_p; nqm = *qm_p; nmi = *mk_p;
    }

    int cont = (qm != qp) ? 1 : 0;
    int cf = __builtin_amdgcn_readfirstlane(cont);
    bool uni = __all(cont == cf);

    float ee[7];
#pragma unroll
    for (int t = 0; t < 7; ++t) ee[t] = __expf(ec[t]);

    // gold-path score: select em[tag] from regs, trans from LDS
    float etag = ec[0];
#pragma unroll
    for (int t = 1; t < 7; ++t) etag = (tg == t) ? ec[t] : etag;
    float ttag = sT[cont][tp * 7 + tg];
    if (mi) { sc += ttag + etag; ++mc; }
    tp = tg; qp = qm;

    if (uni) {
      if (cf != loadedCont) {
#pragma unroll
        for (int k = 0; k < 49; ++k)
          Es[k] = __int_as_float(
              __builtin_amdgcn_readfirstlane(__float_as_int(sE[cf][k])));
        loadedCont = cf;
      }
      if (!__any(mi == 0)) {
#pragma unroll
        for (int s = 0; s < 7; ++s) {
          float a[7] = {0.f,0.f,0.f,0.f,0.f,0.f,0.f};
#pragma unroll
          for (int r = 0; r < 7; ++r) {
            float mr = M[s*7+r];
#pragma unroll
            for (int t = 0; t < 7; ++t) a[t] = fmaf(mr, Es[r*7+t], a[t]);
          }
#pragma unroll
          for (int t = 0; t < 7; ++t) M[s*7+t] = a[t] * ee[t];
        }
      } else {
#pragma unroll
        for (int s = 0; s < 7; ++s) {
          float a[7] = {0.f,0.f,0.f,0.f,0.f,0.f,0.f};
#pragma unroll
          for (int r = 0; r < 7; ++r) {
            float mr = M[s*7+r];
#pragma unroll
            for (int t = 0; t < 7; ++t) a[t] = fmaf(mr, Es[r*7+t], a[t]);
          }
#pragma unroll
          for (int t = 0; t < 7; ++t)
            M[s*7+t] = mi ? a[t] * ee[t] : M[s*7+t];
        }
      }
    } else {
      // divergent cont (rare): per-lane E straight from LDS, few temps
      loadedCont = -1;
#pragma unroll
      for (int s = 0; s < 7; ++s) {
        float a[7] = {0.f,0.f,0.f,0.f,0.f,0.f,0.f};
#pragma unroll
        for (int r = 0; r < 7; ++r) {
          float mr = M[s*7+r];
#pragma unroll
          for (int t = 0; t < 7; ++t)
            a[t] = fmaf(mr, sE[cont][r*7+t], a[t]);
        }
#pragma unroll
        for (int t = 0; t < 7; ++t)
          M[s*7+t] = mi ? a[t] * ee[t] : M[s*7+t];
      }
    }

    if (more) {
#pragma unroll
      for (int t = 0; t < 7; ++t) ec[t] = en[t];
      tg = ntg; qm = nqm; mi = nmi;
    }
  }

  // ---- renormalize own half ----
  float mx = M[0];
#pragma unroll
  for (int t = 1; t < 49; ++t) mx = fmaxf(mx, M[t]);
  float inv = 1.0f / mx;
#pragma unroll
  for (int t = 0; t < 49; ++t) M[t] *= inv;
  float lg = logf(mx);

  // ---- merge halves: record = MA x MB ----
  if (h == 1) {
#pragma unroll
    for (int t = 0; t < 49; ++t) sMB[bl][t] = M[t];
    sAux[bl][0] = sc;
    sAux[bl][1] = (float)mc;
    sAux[bl][2] = lg;
  }
  __syncthreads();
  if (h == 0) {
    sc += sAux[bl][0];
    mc += (int)sAux[bl][1];
    float lsum = lg + sAux[bl][2];

#pragma unroll
    for (int s = 0; s < 7; ++s) {
      float a[7] = {0.f,0.f,0.f,0.f,0.f,0.f,0.f};
#pragma unroll
      for (int r = 0; r < 7; ++r) {
        float mr = M[s*7+r];
#pragma unroll
        for (int t = 0; t < 7; ++t) a[t] = fmaf(mr, sMB[bl][r*7+t], a[t]);
      }
#pragma unroll
      for (int t = 0; t < 7; ++t) M[s*7+t] = a[t];
    }

    float mx2 = M[0];
#pragma unroll
    for (int t = 1; t < 49; ++t) mx2 = fmaxf(mx2, M[t]);
    float inv2 = 1.0f / mx2;

    float outv[REC];
#pragma unroll
    for (int t = 0; t < 49; ++t) outv[t] = M[t] * inv2;
    outv[49] = lsum + logf(mx2);
    outv[50] = sc;
    outv[51] = (float)mc;

    float4* rp = reinterpret_cast<float4*>(recs + ((size_t)c * BB + b) * REC);
#pragma unroll
    for (int k2 = 0; k2 < 13; ++k2)
      rp[k2] = make_float4(outv[4*k2+0], outv[4*k2+1], outv[4*k2+2], outv[4*k2+3]);
  }
}

// ---------------------------------------------------------------------------
// Kernel 2: one wave per batch; sequentially fold the K chunk operators into
// the alpha vector (exp-space, renormalized each step), then finish score/logZ.
// ---------------------------------------------------------------------------
__global__ __launch_bounds__(64)
void crf_combine_kernel(const float* __restrict__ recs,
                        const float* __restrict__ em,
                        const int*   __restrict__ tags,
                        const float* __restrict__ start_t,
                        const float* __restrict__ end_t,
                        float* __restrict__ results,
                        int K) {
  int b = blockIdx.x;
  int j = threadIdx.x;
  __shared__ float lds[REC];

  float al[TT];
#pragma unroll
  for (int t = 0; t < TT; ++t) al[t] = expf(start_t[t] + em[(size_t)b * TT + t]);

  float lacc = 0.f, sc = 0.f, mcf = 0.f;
  float r = (j < REC) ? recs[(size_t)b * REC + j] : 0.f;   // record (c=0, b)

  for (int c = 0; c < K; ++c) {
    if (j < REC) lds[j] = r;
    __syncthreads();
    if (c + 1 < K && j < REC)
      r = recs[((size_t)(c + 1) * BB + b) * REC + j];      // prefetch next

    float nt = 0.f;
    if (j < TT) {
#pragma unroll
      for (int s = 0; s < TT; ++s) nt = fmaf(al[s], lds[s * TT + j], nt);
    }
    float lc  = lds[49];
    float scc = lds[50];
    float mcc = lds[51];
    __syncthreads();

    float na[TT];
#pragma unroll
    for (int t = 0; t < TT; ++t) na[t] = __shfl(nt, t);
    float mx = na[0];
#pragma unroll
    for (int t = 1; t < TT; ++t) mx = fmaxf(mx, na[t]);
    float inv = 1.0f / mx;
#pragma unroll
    for (int t = 0; t < TT; ++t) al[t] = na[t] * inv;
    lacc += logf(mx) + lc;
    sc += scc; mcf += mcc;
  }

  if (j == 0) {
    float z = 0.f;
#pragma unroll
    for (int t = 0; t < TT; ++t) z += al[t] * expf(end_t[t]);
    float logZ = lacc + logf(z);
    int t0 = tags[b];
    float s0 = start_t[t0] + em[(size_t)b * TT + t0];
    int se = (int)mcf - 1;
    int te = tags[(size_t)se * BB + b];
    results[b] = (sc + s0 + end_t[te]) - logZ;
  }
}

// ---------------------------------------------------------------------------
// Kernel 3: deterministic tree-reduce of the 2048 per-batch results.
// ---------------------------------------------------------------------------
__global__ __launch_bounds__(256)
void crf_reduce_kernel(const float* __restrict__ results, float* __restrict__ out) {
  __shared__ float s[256];
  int t = threadIdx.x;
  float v = 0.f;
  for (int i = t; i < BB; i += 256) v += results[i];
  s[t] = v;
  __syncthreads();
  for (int off = 128; off > 0; off >>= 1) {
    if (t < off) s[t] += s[t + off];
    __syncthreads();
  }
  if (t == 0) out[0] = s[0];
}

extern "C" void kernel_launch(void* const* d_in, const int* in_sizes, int n_in,
                              void* d_out, int out_size, void* d_ws, size_t ws_size,
                              hipStream_t stream) {
  const float* em      = (const float*)d_in[0];
  const int*   tags    = (const int*)d_in[1];
  const int*   qmask   = (const int*)d_in[2];
  const int*   mask    = (const int*)d_in[3];
  const float* start_t = (const float*)d_in[4];
  const float* end_t   = (const float*)d_in[5];
  const float* self_t  = (const float*)d_in[6];
  const float* other_t = (const float*)d_in[7];

  float* recs = (float*)d_ws;

  // choose chunk count to fit workspace: K*B*REC*4 + B*4 bytes
  int K = 64;
  auto need = [](int k) { return (size_t)k * BB * REC * 4 + (size_t)BB * 4; };
  if      (ws_size >= need(64)) K = 64;
  else if (ws_size >= need(32)) K = 32;
  else if (ws_size >= need(16)) K = 16;
  else if (ws_size >= need(8))  K = 8;
  else                          K = 4;

  float* results = recs + (size_t)K * BB * REC;

  int threads = 256;
  int blocks = (K * BB) / 128;   // 128 chunks per block, 2 threads each
  switch (K) {
    case 64: crf_chunk_kernel<64><<<blocks, threads, 0, stream>>>(em, tags, qmask, mask, self_t, other_t, recs); break;
    case 32: crf_chunk_kernel<32><<<blocks, threads, 0, stream>>>(em, tags, qmask, mask, self_t, other_t, recs); break;
    case 16: crf_chunk_kernel<16><<<blocks, threads, 0, stream>>>(em, tags, qmask, mask, self_t, other_t, recs); break;
    case 8:  crf_chunk_kernel<8 ><<<blocks, threads, 0, stream>>>(em, tags, qmask, mask, self_t, other_t, recs); break;
    default: crf_chunk_kernel<4 ><<<blocks, threads, 0, stream>>>(em, tags, qmask, mask, self_t, other_t, recs); break;
  }

  crf_combine_kernel<<<BB, 64, 0, stream>>>(recs, em, tags, start_t, end_t, results, K);
  crf_reduce_kernel<<<1, 256, 0, stream>>>(results, (float*)d_out);
}

// Round 8
// 91.512 us; speedup vs baseline: 3.3478x; 3.3478x over previous
//
#include <hip/hip_runtime.h>
#include <hip/hip_bf16.h>

#define LSEQ 2048
#define BB   2048
#define TT   7
#define REC  52   // 49 matrix + scale + score + maskcnt (float), 208 B = 16B-aligned

// ---------------------------------------------------------------------------
// Kernel 1: 2 threads per (batch, chunk); thread h in {0,1} builds the
// composite operator for its half-chunk (C/2 steps) in exp-space:
//   M <- (M x E) o colscale(exp(em_i)),  E = exp(transitions) per cont flag.
// E is held in SGPRs via readfirstlane when the cont flag is wave-uniform
// (the common case); a register-light LDS fallback handles divergence.
// Each half renormalizes, then h=1 publishes via LDS and h=0 merges
// (M = MA x MB), renorms again, and writes the 52-float record.
// NOTE: no min-wave launch_bounds — forcing 4 blocks/CU clamps VGPR to 64
// and spills M[49] to scratch (R5/R7 post-mortems: WRITE_SIZE 26 MB -> 700 MB).
// ---------------------------------------------------------------------------
template<int K>
__global__ __launch_bounds__(256)
void crf_chunk_kernel(const float* __restrict__ em,
                      const int*   __restrict__ tags,
                      const int*   __restrict__ qmask,
                      const int*   __restrict__ mask,
                      const float* __restrict__ self_t,
                      const float* __restrict__ other_t,
                      float* __restrict__ recs) {
  constexpr int C  = LSEQ / K;   // steps per chunk
  constexpr int C2 = C / 2;      // steps per thread
  __shared__ float sE[2][49];    // exp(transitions): [0]=self, [1]=other
  __shared__ float sT[2][49];    // raw transitions (gold-path score)
  __shared__ float sMB[128][49]; // second-half matrices (stride 49 is odd: conflict-free)
  __shared__ float sAux[128][3]; // sc, mc, logscale from h=1

  int tid = threadIdx.x;
  if (tid < 49) {
    float sv = self_t[tid];
    float ov = other_t[tid];
    sE[0][tid] = __expf(sv);
    sE[1][tid] = __expf(ov);
    sT[0][tid] = sv;
    sT[1][tid] = ov;
  }
  __syncthreads();

  int h  = tid >> 7;             // half: 0 = first C/2 steps, 1 = second
  int bl = tid & 127;            // chunk slot within block
  int chunkIdx = blockIdx.x * 128 + bl;
  int b = chunkIdx & (BB - 1);   // varies across lanes
  int c = chunkIdx >> 11;        // uniform within block (2048 % 128 == 0)

  float M[49];
#pragma unroll
  for (int s = 0; s < 7; ++s)
#pragma unroll
    for (int t = 0; t < 7; ++t) M[s*7+t] = (s == t) ? 1.0f : 0.0f;

  float sc = 0.0f;
  int   mc = 0;
  int i0    = c * C + h * C2;
  int i_end = i0 + C2;
  int tp, qp;
  if (i0 == 0) {                 // c==0, h==0: step 0 is the alpha-init
    mc = mask[b];
    tp = tags[b];
    qp = qmask[b];
    i0 = 1;
  } else {
    tp = tags[(size_t)(i0 - 1) * BB + b];
    qp = qmask[(size_t)(i0 - 1) * BB + b];
  }

  const float* em_p = em    + ((size_t)i0 * BB + b) * TT;
  const int*   qm_p = qmask + (size_t)i0 * BB + b;
  const int*   mk_p = mask  + (size_t)i0 * BB + b;
  const int*   tg_p = tags  + (size_t)i0 * BB + b;

  float Es[49];                  // SGPR-resident when cont is wave-uniform
  int loadedCont = -1;

  // software pipeline: current step's inputs in regs, next prefetched
  float ec[7];
#pragma unroll
  for (int t = 0; t < 7; ++t) ec[t] = em_p[t];
  int tg = *tg_p, qm = *qm_p, mi = *mk_p;

  for (int i = i0; i < i_end; ++i) {
    em_p += (size_t)BB * TT;
    qm_p += BB; mk_p += BB; tg_p += BB;
    float en[7]; int ntg = 0, nqm = 0, nmi = 0;
    bool more = (i + 1 < i_end);          // uniform (c,h uniform per wave)
    if (more) {
#pragma unroll
      for (int t = 0; t < 7; ++t) en[t] = em_p[t];
      ntg = *tg_p; nqm = *qm_p; nmi = *mk_p;
    }

    int cont = (qm != qp) ? 1 : 0;
    int cf = __builtin_amdgcn_readfirstlane(cont);
    bool uni = __all(cont == cf);

    float ee[7];
#pragma unroll
    for (int t = 0; t < 7; ++t) ee[t] = __expf(ec[t]);

    // gold-path score: select em[tag] from regs, trans from LDS
    float etag = ec[0];
#pragma unroll
    for (int t = 1; t < 7; ++t) etag = (tg == t) ? ec[t] : etag;
    float ttag = sT[cont][tp * 7 + tg];
    if (mi) { sc += ttag + etag; ++mc; }
    tp = tg; qp = qm;

    if (uni) {
      if (cf != loadedCont) {
#pragma unroll
        for (int k = 0; k < 49; ++k)
          Es[k] = __int_as_float(
              __builtin_amdgcn_readfirstlane(__float_as_int(sE[cf][k])));
        loadedCont = cf;
      }
      if (!__any(mi == 0)) {
#pragma unroll
        for (int s = 0; s < 7; ++s) {
          float a[7] = {0.f,0.f,0.f,0.f,0.f,0.f,0.f};
#pragma unroll
          for (int r = 0; r < 7; ++r) {
            float mr = M[s*7+r];
#pragma unroll
            for (int t = 0; t < 7; ++t) a[t] = fmaf(mr, Es[r*7+t], a[t]);
          }
#pragma unroll
          for (int t = 0; t < 7; ++t) M[s*7+t] = a[t] * ee[t];
        }
      } else {
#pragma unroll
        for (int s = 0; s < 7; ++s) {
          float a[7] = {0.f,0.f,0.f,0.f,0.f,0.f,0.f};
#pragma unroll
          for (int r = 0; r < 7; ++r) {
            float mr = M[s*7+r];
#pragma unroll
            for (int t = 0; t < 7; ++t) a[t] = fmaf(mr, Es[r*7+t], a[t]);
          }
#pragma unroll
          for (int t = 0; t < 7; ++t)
            M[s*7+t] = mi ? a[t] * ee[t] : M[s*7+t];
        }
      }
    } else {
      // divergent cont (rare): per-lane E straight from LDS, few temps
      loadedCont = -1;
#pragma unroll
      for (int s = 0; s < 7; ++s) {
        float a[7] = {0.f,0.f,0.f,0.f,0.f,0.f,0.f};
#pragma unroll
        for (int r = 0; r < 7; ++r) {
          float mr = M[s*7+r];
#pragma unroll
          for (int t = 0; t < 7; ++t)
            a[t] = fmaf(mr, sE[cont][r*7+t], a[t]);
        }
#pragma unroll
        for (int t = 0; t < 7; ++t)
          M[s*7+t] = mi ? a[t] * ee[t] : M[s*7+t];
      }
    }

    if (more) {
#pragma unroll
      for (int t = 0; t < 7; ++t) ec[t] = en[t];
      tg = ntg; qm = nqm; mi = nmi;
    }
  }

  // ---- renormalize own half ----
  float mx = M[0];
#pragma unroll
  for (int t = 1; t < 49; ++t) mx = fmaxf(mx, M[t]);
  float inv = 1.0f / mx;
#pragma unroll
  for (int t = 0; t < 49; ++t) M[t] *= inv;
  float lg = logf(mx);

  // ---- merge halves: record = MA x MB ----
  if (h == 1) {
#pragma unroll
    for (int t = 0; t < 49; ++t) sMB[bl][t] = M[t];
    sAux[bl][0] = sc;
    sAux[bl][1] = (float)mc;
    sAux[bl][2] = lg;
  }
  __syncthreads();
  if (h == 0) {
    sc += sAux[bl][0];
    mc += (int)sAux[bl][1];
    float lsum = lg + sAux[bl][2];

#pragma unroll
    for (int s = 0; s < 7; ++s) {
      float a[7] = {0.f,0.f,0.f,0.f,0.f,0.f,0.f};
#pragma unroll
      for (int r = 0; r < 7; ++r) {
        float mr = M[s*7+r];
#pragma unroll
        for (int t = 0; t < 7; ++t) a[t] = fmaf(mr, sMB[bl][r*7+t], a[t]);
      }
#pragma unroll
      for (int t = 0; t < 7; ++t) M[s*7+t] = a[t];
    }

    float mx2 = M[0];
#pragma unroll
    for (int t = 1; t < 49; ++t) mx2 = fmaxf(mx2, M[t]);
    float inv2 = 1.0f / mx2;

    float outv[REC];
#pragma unroll
    for (int t = 0; t < 49; ++t) outv[t] = M[t] * inv2;
    outv[49] = lsum + logf(mx2);
    outv[50] = sc;
    outv[51] = (float)mc;

    float4* rp = reinterpret_cast<float4*>(recs + ((size_t)c * BB + b) * REC);
#pragma unroll
    for (int k2 = 0; k2 < 13; ++k2)
      rp[k2] = make_float4(outv[4*k2+0], outv[4*k2+1], outv[4*k2+2], outv[4*k2+3]);
  }
}

// ---------------------------------------------------------------------------
// Kernel 2: one wave per batch; sequentially fold the K chunk operators into
// the alpha vector (exp-space, renormalized each step), then finish score/logZ.
// ---------------------------------------------------------------------------
__global__ __launch_bounds__(64)
void crf_combine_kernel(const float* __restrict__ recs,
                        const float* __restrict__ em,
                        const int*   __restrict__ tags,
                        const float* __restrict__ start_t,
                        const float* __restrict__ end_t,
                        float* __restrict__ results,
                        int K) {
  int b = blockIdx.x;
  int j = threadIdx.x;
  __shared__ float lds[REC];

  float al[TT];
#pragma unroll
  for (int t = 0; t < TT; ++t) al[t] = expf(start_t[t] + em[(size_t)b * TT + t]);

  float lacc = 0.f, sc = 0.f, mcf = 0.f;
  float r = (j < REC) ? recs[(size_t)b * REC + j] : 0.f;   // record (c=0, b)

  for (int c = 0; c < K; ++c) {
    if (j < REC) lds[j] = r;
    __syncthreads();
    if (c + 1 < K && j < REC)
      r = recs[((size_t)(c + 1) * BB + b) * REC + j];      // prefetch next

    float nt = 0.f;
    if (j < TT) {
#pragma unroll
      for (int s = 0; s < TT; ++s) nt = fmaf(al[s], lds[s * TT + j], nt);
    }
    float lc  = lds[49];
    float scc = lds[50];
    float mcc = lds[51];
    __syncthreads();

    float na[TT];
#pragma unroll
    for (int t = 0; t < TT; ++t) na[t] = __shfl(nt, t);
    float mx = na[0];
#pragma unroll
    for (int t = 1; t < TT; ++t) mx = fmaxf(mx, na[t]);
    float inv = 1.0f / mx;
#pragma unroll
    for (int t = 0; t < TT; ++t) al[t] = na[t] * inv;
    lacc += logf(mx) + lc;
    sc += scc; mcf += mcc;
  }

  if (j == 0) {
    float z = 0.f;
#pragma unroll
    for (int t = 0; t < TT; ++t) z += al[t] * expf(end_t[t]);
    float logZ = lacc + logf(z);
    int t0 = tags[b];
    float s0 = start_t[t0] + em[(size_t)b * TT + t0];
    int se = (int)mcf - 1;
    int te = tags[(size_t)se * BB + b];
    results[b] = (sc + s0 + end_t[te]) - logZ;
  }
}

// ---------------------------------------------------------------------------
// Kernel 3: deterministic tree-reduce of the 2048 per-batch results.
// ---------------------------------------------------------------------------
__global__ __launch_bounds__(256)
void crf_reduce_kernel(const float* __restrict__ results, float* __restrict__ out) {
  __shared__ float s[256];
  int t = threadIdx.x;
  float v = 0.f;
  for (int i = t; i < BB; i += 256) v += results[i];
  s[t] = v;
  __syncthreads();
  for (int off = 128; off > 0; off >>= 1) {
    if (t < off) s[t] += s[t + off];
    __syncthreads();
  }
  if (t == 0) out[0] = s[0];
}

extern "C" void kernel_launch(void* const* d_in, const int* in_sizes, int n_in,
                              void* d_out, int out_size, void* d_ws, size_t ws_size,
                              hipStream_t stream) {
  const float* em      = (const float*)d_in[0];
  const int*   tags    = (const int*)d_in[1];
  const int*   qmask   = (const int*)d_in[2];
  const int*   mask    = (const int*)d_in[3];
  const float* start_t = (const float*)d_in[4];
  const float* end_t   = (const float*)d_in[5];
  const float* self_t  = (const float*)d_in[6];
  const float* other_t = (const float*)d_in[7];

  float* recs = (float*)d_ws;

  // choose chunk count to fit workspace: K*B*REC*4 + B*4 bytes
  int K = 64;
  auto need = [](int k) { return (size_t)k * BB * REC * 4 + (size_t)BB * 4; };
  if      (ws_size >= need(64)) K = 64;
  else if (ws_size >= need(32)) K = 32;
  else if (ws_size >= need(16)) K = 16;
  else if (ws_size >= need(8))  K = 8;
  else                          K = 4;

  float* results = recs + (size_t)K * BB * REC;

  int threads = 256;
  int blocks = (K * BB) / 128;   // 128 chunks per block, 2 threads each
  switch (K) {
    case 64: crf_chunk_kernel<64><<<blocks, threads, 0, stream>>>(em, tags, qmask, mask, self_t, other_t, recs); break;
    case 32: crf_chunk_kernel<32><<<blocks, threads, 0, stream>>>(em, tags, qmask, mask, self_t, other_t, recs); break;
    case 16: crf_chunk_kernel<16><<<blocks, threads, 0, stream>>>(em, tags, qmask, mask, self_t, other_t, recs); break;
    case 8:  crf_chunk_kernel<8 ><<<blocks, threads, 0, stream>>>(em, tags, qmask, mask, self_t, other_t, recs); break;
    default: crf_chunk_kernel<4 ><<<blocks, threads, 0, stream>>>(em, tags, qmask, mask, self_t, other_t, recs); break;
  }

  crf_combine_kernel<<<BB, 64, 0, stream>>>(recs, em, tags, start_t, end_t, results, K);
  crf_reduce_kernel<<<1, 256, 0, stream>>>(results, (float*)d_out);
}